// Round 1
// baseline (1927.032 us; speedup 1.0000x reference)
//
#include <hip/hip_runtime.h>
#include <math.h>

// Problem constants (B=4, T=2048, C=1024, H=16, Dh=64)
#define TSEQ 2048
#define CDIM 1024
#define NH   16
#define DH   64
#define BKK  16   // GEMM K-tile

// ---------------------------------------------------------------------------
// QKV projection: x(8192x1024) @ W(1024x3072) + b -> scatter to Q/K/V (B,H,T,Dh)
// 128x128 tile, 256 threads, 8x8 per thread (split 4+4), fp32.
// ---------------------------------------------------------------------------
__global__ __launch_bounds__(256) void qkv_gemm(
    const float* __restrict__ A, const float* __restrict__ W,
    const float* __restrict__ bias,
    float* __restrict__ Qo, float* __restrict__ Ko, float* __restrict__ Vo)
{
    __shared__ float As[BKK][132];  // [k][m], +4 pad keeps float4 alignment, 2-way max
    __shared__ float Bs[BKK][132];  // [k][n]
    const int tid = threadIdx.x;
    const int tx = tid & 15, ty = tid >> 4;
    const int mb = blockIdx.y * 128;
    const int nb = blockIdx.x * 128;
    const int NDIM = 3072, KDIM = 1024;

    float acc[8][8];
#pragma unroll
    for (int i = 0; i < 8; i++)
#pragma unroll
        for (int j = 0; j < 8; j++) acc[i][j] = 0.f;

    const int arow = tid >> 2;         // 0..63
    const int akc  = (tid & 3) << 2;   // 0,4,8,12
    const int brow = tid >> 5;         // 0..7
    const int bcol = (tid & 31) << 2;  // 0..124

    for (int kb = 0; kb < KDIM; kb += BKK) {
#pragma unroll
        for (int r = 0; r < 2; r++) {
            int row = arow + r * 64;
            float4 a = *(const float4*)&A[(mb + row) * KDIM + kb + akc];
            As[akc + 0][row] = a.x;
            As[akc + 1][row] = a.y;
            As[akc + 2][row] = a.z;
            As[akc + 3][row] = a.w;
        }
#pragma unroll
        for (int r = 0; r < 2; r++) {
            int kr = brow + r * 8;
            *(float4*)&Bs[kr][bcol] = *(const float4*)&W[(kb + kr) * NDIM + nb + bcol];
        }
        __syncthreads();
#pragma unroll
        for (int kk = 0; kk < BKK; kk++) {
            float4 a0 = *(const float4*)&As[kk][ty * 4];
            float4 a1 = *(const float4*)&As[kk][ty * 4 + 64];
            float4 b0 = *(const float4*)&Bs[kk][tx * 4];
            float4 b1 = *(const float4*)&Bs[kk][tx * 4 + 64];
            float av[8] = {a0.x, a0.y, a0.z, a0.w, a1.x, a1.y, a1.z, a1.w};
            float bv[8] = {b0.x, b0.y, b0.z, b0.w, b1.x, b1.y, b1.z, b1.w};
#pragma unroll
            for (int i = 0; i < 8; i++)
#pragma unroll
                for (int j = 0; j < 8; j++)
                    acc[i][j] = fmaf(av[i], bv[j], acc[i][j]);
        }
        __syncthreads();
    }

    // Epilogue: bias + scatter. Tile N-base is 128-aligned; q/k/v boundary (1024)
    // and head boundary (64) never split a 4-wide float4 group.
#pragma unroll
    for (int ii = 0; ii < 8; ii++) {
        int row = (ii < 4) ? (ty * 4 + ii) : (64 + ty * 4 + ii - 4);
        int m = mb + row;
        int b = m >> 11, t = m & 2047;
#pragma unroll
        for (int jh = 0; jh < 2; jh++) {
            int c = jh * 64 + tx * 4;
            int n = nb + c;
            int which = n >> 10;
            int h = (n >> 6) & 15;
            int d = n & 63;
            float4 bz = *(const float4*)&bias[n];
            float4 o;
            o.x = acc[ii][jh * 4 + 0] + bz.x;
            o.y = acc[ii][jh * 4 + 1] + bz.y;
            o.z = acc[ii][jh * 4 + 2] + bz.z;
            o.w = acc[ii][jh * 4 + 3] + bz.w;
            float* dst = (which == 0) ? Qo : ((which == 1) ? Ko : Vo);
            *(float4*)&dst[(((b * NH + h) * TSEQ + t) << 6) + d] = o;
        }
    }
}

// ---------------------------------------------------------------------------
// Output projection: Oc(8192x1024) @ W_out(1024x1024) + b_out -> out
// ---------------------------------------------------------------------------
__global__ __launch_bounds__(256) void out_gemm(
    const float* __restrict__ A, const float* __restrict__ W,
    const float* __restrict__ bias, float* __restrict__ Out)
{
    __shared__ float As[BKK][132];
    __shared__ float Bs[BKK][132];
    const int tid = threadIdx.x;
    const int tx = tid & 15, ty = tid >> 4;
    const int mb = blockIdx.y * 128;
    const int nb = blockIdx.x * 128;
    const int NDIM = 1024, KDIM = 1024;

    float acc[8][8];
#pragma unroll
    for (int i = 0; i < 8; i++)
#pragma unroll
        for (int j = 0; j < 8; j++) acc[i][j] = 0.f;

    const int arow = tid >> 2;
    const int akc  = (tid & 3) << 2;
    const int brow = tid >> 5;
    const int bcol = (tid & 31) << 2;

    for (int kb = 0; kb < KDIM; kb += BKK) {
#pragma unroll
        for (int r = 0; r < 2; r++) {
            int row = arow + r * 64;
            float4 a = *(const float4*)&A[(mb + row) * KDIM + kb + akc];
            As[akc + 0][row] = a.x;
            As[akc + 1][row] = a.y;
            As[akc + 2][row] = a.z;
            As[akc + 3][row] = a.w;
        }
#pragma unroll
        for (int r = 0; r < 2; r++) {
            int kr = brow + r * 8;
            *(float4*)&Bs[kr][bcol] = *(const float4*)&W[(kb + kr) * NDIM + nb + bcol];
        }
        __syncthreads();
#pragma unroll
        for (int kk = 0; kk < BKK; kk++) {
            float4 a0 = *(const float4*)&As[kk][ty * 4];
            float4 a1 = *(const float4*)&As[kk][ty * 4 + 64];
            float4 b0 = *(const float4*)&Bs[kk][tx * 4];
            float4 b1 = *(const float4*)&Bs[kk][tx * 4 + 64];
            float av[8] = {a0.x, a0.y, a0.z, a0.w, a1.x, a1.y, a1.z, a1.w};
            float bv[8] = {b0.x, b0.y, b0.z, b0.w, b1.x, b1.y, b1.z, b1.w};
#pragma unroll
            for (int i = 0; i < 8; i++)
#pragma unroll
                for (int j = 0; j < 8; j++)
                    acc[i][j] = fmaf(av[i], bv[j], acc[i][j]);
        }
        __syncthreads();
    }

#pragma unroll
    for (int ii = 0; ii < 8; ii++) {
        int row = (ii < 4) ? (ty * 4 + ii) : (64 + ty * 4 + ii - 4);
        int m = mb + row;
#pragma unroll
        for (int jh = 0; jh < 2; jh++) {
            int c = jh * 64 + tx * 4;
            int n = nb + c;
            float4 bz = *(const float4*)&bias[n];
            float4 o;
            o.x = acc[ii][jh * 4 + 0] + bz.x;
            o.y = acc[ii][jh * 4 + 1] + bz.y;
            o.z = acc[ii][jh * 4 + 2] + bz.z;
            o.w = acc[ii][jh * 4 + 3] + bz.w;
            *(float4*)&Out[m * NDIM + n] = o;
        }
    }
}

// ---------------------------------------------------------------------------
// Flash attention fp32: one block per (b,h,q-tile of 64). Online softmax.
// Q staged transposed [d][qrow] (scaled by 1/sqrt(Dh)); K staged transposed
// [d][kcol] into KPt; after S-compute, P is written [k][qrow] into the SAME
// buffer (saves 17 KB LDS -> 3 blocks/CU). All compute reads are
// broadcast/2-way bank patterns.
// ---------------------------------------------------------------------------
__global__ __launch_bounds__(256) void attn_fwd(
    const float* __restrict__ Q, const float* __restrict__ K,
    const float* __restrict__ V, float* __restrict__ Oc)
{
    __shared__ float Qt[64][68];
    __shared__ float KPt[64][68];
    __shared__ float Vs[64][68];
    const int tid = threadIdx.x;
    const int tx = tid & 15, ty = tid >> 4;
    const int qt = blockIdx.x & 31;
    const int bh = blockIdx.x >> 5;
    const float* Qb = Q + bh * TSEQ * DH;
    const float* Kb = K + bh * TSEQ * DH;
    const float* Vb = V + bh * TSEQ * DH;

    const int lrow = tid >> 2;        // 0..63
    const int lc0  = (tid & 3) << 4;  // 0,16,32,48

    // Load Q tile transposed + pre-scaled
#pragma unroll
    for (int u = 0; u < 4; u++) {
        int col = lc0 + u * 4;
        float4 q = *(const float4*)&Qb[((qt * 64 + lrow) << 6) + col];
        Qt[col + 0][lrow] = q.x * 0.125f;
        Qt[col + 1][lrow] = q.y * 0.125f;
        Qt[col + 2][lrow] = q.z * 0.125f;
        Qt[col + 3][lrow] = q.w * 0.125f;
    }

    float m_r[4], l_r[4], o_acc[4][4];
#pragma unroll
    for (int i = 0; i < 4; i++) {
        m_r[i] = -INFINITY; l_r[i] = 0.f;
#pragma unroll
        for (int j = 0; j < 4; j++) o_acc[i][j] = 0.f;
    }

    for (int kt = 0; kt <= qt; kt++) {
        __syncthreads();  // prev PV done (and Qt visible on first iter)
        // Stage K transposed + V row-major
#pragma unroll
        for (int u = 0; u < 4; u++) {
            int col = lc0 + u * 4;
            float4 k4 = *(const float4*)&Kb[((kt * 64 + lrow) << 6) + col];
            KPt[col + 0][lrow] = k4.x;
            KPt[col + 1][lrow] = k4.y;
            KPt[col + 2][lrow] = k4.z;
            KPt[col + 3][lrow] = k4.w;
            *(float4*)&Vs[lrow][col] = *(const float4*)&Vb[((kt * 64 + lrow) << 6) + col];
        }
        __syncthreads();

        // S tile: qrows ty*4+i, kcols tx*4+j
        float s[4][4];
#pragma unroll
        for (int i = 0; i < 4; i++)
#pragma unroll
            for (int j = 0; j < 4; j++) s[i][j] = 0.f;
#pragma unroll 8
        for (int d = 0; d < 64; d++) {
            float4 qa  = *(const float4*)&Qt[d][ty * 4];
            float4 kb4 = *(const float4*)&KPt[d][tx * 4];
            float qv[4] = {qa.x, qa.y, qa.z, qa.w};
            float kv[4] = {kb4.x, kb4.y, kb4.z, kb4.w};
#pragma unroll
            for (int i = 0; i < 4; i++)
#pragma unroll
                for (int j = 0; j < 4; j++)
                    s[i][j] = fmaf(qv[i], kv[j], s[i][j]);
        }
        if (kt == qt) {
#pragma unroll
            for (int i = 0; i < 4; i++)
#pragma unroll
                for (int j = 0; j < 4; j++)
                    if (tx * 4 + j > ty * 4 + i) s[i][j] = -INFINITY;
        }

        // Online softmax (row groups = 16 consecutive lanes; xor masks stay inside)
        float p[4][4];
#pragma unroll
        for (int i = 0; i < 4; i++) {
            float tm = fmaxf(fmaxf(s[i][0], s[i][1]), fmaxf(s[i][2], s[i][3]));
            tm = fmaxf(tm, __shfl_xor(tm, 1));
            tm = fmaxf(tm, __shfl_xor(tm, 2));
            tm = fmaxf(tm, __shfl_xor(tm, 4));
            tm = fmaxf(tm, __shfl_xor(tm, 8));
            float mnew = fmaxf(m_r[i], tm);
            float corr = __expf(m_r[i] - mnew);  // first iter: exp(-inf)=0
            float rs = 0.f;
#pragma unroll
            for (int j = 0; j < 4; j++) {
                p[i][j] = __expf(s[i][j] - mnew);
                rs += p[i][j];
            }
            rs += __shfl_xor(rs, 1);
            rs += __shfl_xor(rs, 2);
            rs += __shfl_xor(rs, 4);
            rs += __shfl_xor(rs, 8);
            l_r[i] = l_r[i] * corr + rs;
            m_r[i] = mnew;
#pragma unroll
            for (int j = 0; j < 4; j++) o_acc[i][j] *= corr;
        }

        __syncthreads();  // all KPt (K) reads done before overwrite with P
#pragma unroll
        for (int i = 0; i < 4; i++)
#pragma unroll
            for (int j = 0; j < 4; j++)
                KPt[tx * 4 + j][ty * 4 + i] = p[i][j];
        __syncthreads();

        // O += P @ V : orows ty*4+i, dcols tx*4+j
#pragma unroll 8
        for (int k = 0; k < 64; k++) {
            float4 pa  = *(const float4*)&KPt[k][ty * 4];
            float4 vb4 = *(const float4*)&Vs[k][tx * 4];
            float pv[4] = {pa.x, pa.y, pa.z, pa.w};
            float vv[4] = {vb4.x, vb4.y, vb4.z, vb4.w};
#pragma unroll
            for (int i = 0; i < 4; i++)
#pragma unroll
                for (int j = 0; j < 4; j++)
                    o_acc[i][j] = fmaf(pv[i], vv[j], o_acc[i][j]);
        }
    }

    // Epilogue: normalize, write concat layout (B,T,C)
    const int b = bh >> 4, h = bh & 15;
#pragma unroll
    for (int i = 0; i < 4; i++) {
        float inv = 1.0f / l_r[i];
        int t = qt * 64 + ty * 4 + i;
        float4 o;
        o.x = o_acc[i][0] * inv;
        o.y = o_acc[i][1] * inv;
        o.z = o_acc[i][2] * inv;
        o.w = o_acc[i][3] * inv;
        *(float4*)&Oc[(b * TSEQ + t) * CDIM + h * DH + tx * 4] = o;
    }
}

extern "C" void kernel_launch(void* const* d_in, const int* in_sizes, int n_in,
                              void* d_out, int out_size, void* d_ws, size_t ws_size,
                              hipStream_t stream) {
    const float* x     = (const float*)d_in[0];
    const float* W_qkv = (const float*)d_in[1];
    const float* b_qkv = (const float*)d_in[2];
    const float* W_out = (const float*)d_in[3];
    const float* b_out = (const float*)d_in[4];
    float* out = (float*)d_out;

    // Workspace: Q,K,V in (B,H,T,Dh) + attention concat (B,T,C), all fp32.
    // 4 x 8388608 floats = 128 MB.
    float* Qw  = (float*)d_ws;
    float* Kw  = Qw + 8388608;
    float* Vw  = Kw + 8388608;
    float* Ocw = Vw + 8388608;

    qkv_gemm<<<dim3(24, 64), 256, 0, stream>>>(x, W_qkv, b_qkv, Qw, Kw, Vw);
    attn_fwd<<<dim3(2048), 256, 0, stream>>>(Qw, Kw, Vw, Ocw);
    out_gemm<<<dim3(8, 64), 256, 0, stream>>>(Ocw, W_out, b_out, out);
}

// Round 2
// 408.442 us; speedup vs baseline: 4.7180x; 4.7180x over previous
//
#include <hip/hip_runtime.h>
#include <math.h>

typedef __attribute__((ext_vector_type(8))) short bf16x8;
typedef __attribute__((ext_vector_type(4))) float f32x4;
typedef unsigned short u16;
typedef unsigned int u32;

#define TSEQ 2048
#define NH   16
#define DH   64
#define CDIM 1024

__device__ __forceinline__ u16 f2bf(float f) {
    union { float f; u32 u; } v; v.f = f;
    u32 r = v.u + 0x7fffu + ((v.u >> 16) & 1u);
    return (u16)(r >> 16);
}

__device__ __forceinline__ void gl_lds16(const void* g, void* l) {
    __builtin_amdgcn_global_load_lds(
        (const __attribute__((address_space(1))) u32*)g,
        (__attribute__((address_space(3))) u32*)l, 16, 0, 0);
}

#define MFMA16(a, b, c) __builtin_amdgcn_mfma_f32_16x16x32_bf16(a, b, c, 0, 0, 0)

// ---------------------------------------------------------------------------
// fp32 -> bf16 elementwise (x)
// ---------------------------------------------------------------------------
__global__ __launch_bounds__(256) void cvt_bf16(const float* __restrict__ in,
                                                u16* __restrict__ out, int n) {
    int i = (blockIdx.x * 256 + threadIdx.x) * 8;
    if (i >= n) return;
    float4 a = *(const float4*)(in + i);
    float4 b = *(const float4*)(in + i + 4);
    u16 o[8] = {f2bf(a.x), f2bf(a.y), f2bf(a.z), f2bf(a.w),
                f2bf(b.x), f2bf(b.y), f2bf(b.z), f2bf(b.w)};
    *(uint4*)(out + i) = *(const uint4*)o;
}

// ---------------------------------------------------------------------------
// fp32 W[K][N] -> bf16 Wt[N][K]  (32x32 tiles, block (32,8))
// ---------------------------------------------------------------------------
__global__ __launch_bounds__(256) void tr_w_bf16(const float* __restrict__ Wf,
                                                 u16* __restrict__ Wt, int K, int N) {
    __shared__ float tile[32][33];
    int n0 = blockIdx.x * 32, k0 = blockIdx.y * 32;
    int tx = threadIdx.x, ty = threadIdx.y;
#pragma unroll
    for (int r = 0; r < 4; r++)
        tile[ty + r * 8][tx] = Wf[(k0 + ty + r * 8) * N + n0 + tx];
    __syncthreads();
#pragma unroll
    for (int r = 0; r < 4; r++)
        Wt[(n0 + ty + r * 8) * K + k0 + tx] = f2bf(tile[tx][ty + r * 8]);
}

// ---------------------------------------------------------------------------
// bf16 V[bh][T][Dh] -> bf16 Vt[bh][Dh][T]  (64x64 tiles)
// ---------------------------------------------------------------------------
__global__ __launch_bounds__(256) void tr_v_bf16(const u16* __restrict__ V,
                                                 u16* __restrict__ Vt) {
    __shared__ u16 Vl[64][72];  // stride 72: 16B-aligned rows, spread col reads
    const int tt = blockIdx.x, bh = blockIdx.y;
    const u16* src = V + (bh * TSEQ + tt * 64) * DH;
    const int tid = threadIdx.x;
#pragma unroll
    for (int r = 0; r < 2; r++) {
        int idx = r * 256 + tid;       // granule: row=t (64), h = d-granule (8)
        int row = idx >> 3, h = idx & 7;
        uint4 d4 = *(const uint4*)(src + row * DH + h * 8);
        *(uint4*)(&Vl[row][h * 8]) = d4;
    }
    __syncthreads();
    u16* dstb = Vt + bh * DH * TSEQ + tt * 64;
#pragma unroll
    for (int r = 0; r < 2; r++) {
        int idx = r * 256 + tid;       // granule: row=d (64), ht = t-granule (8)
        int d = idx >> 3, ht = idx & 7;
        u16 o[8];
#pragma unroll
        for (int e = 0; e < 8; e++) o[e] = Vl[ht * 8 + e][d];
        *(uint4*)(dstb + d * TSEQ + ht * 8) = *(const uint4*)o;
    }
}

// ---------------------------------------------------------------------------
// QKV GEMM bf16: A[8192][1024] @ Wt[3072][1024]^T + b -> Q/K/V bf16 (B,H,T,Dh)
// m97 structure: 128x128 tile, BK=32, 4 waves, global_load_lds w=16.
// ---------------------------------------------------------------------------
__global__ __launch_bounds__(256) void qkv_gemm_bf(
    const u16* __restrict__ A, const u16* __restrict__ Bt,
    const float* __restrict__ bias,
    u16* __restrict__ Qo, u16* __restrict__ Ko, u16* __restrict__ Vo) {
    __shared__ u16 Al[128 * 32];
    __shared__ u16 Bl[128 * 32];
    const int tid = threadIdx.x;
    const int lane = tid & 63, w = tid >> 6;
    const int l15 = lane & 15, l4 = lane >> 4;
    const int wm = w >> 1, wn = w & 1;
    const int mb = blockIdx.y * 128, nb = blockIdx.x * 128;
    const int KD = 1024;

    f32x4 zero = {0.f, 0.f, 0.f, 0.f};
    f32x4 acc[4][4];
#pragma unroll
    for (int i = 0; i < 4; i++)
#pragma unroll
        for (int j = 0; j < 4; j++) acc[i][j] = zero;

    for (int kb = 0; kb < KD; kb += 32) {
        __syncthreads();
#pragma unroll
        for (int r = 0; r < 2; r++) {
            int idx = r * 256 + tid;   // granule: row (128), h = k-granule (4)
            int row = idx >> 2, h = idx & 3;
            gl_lds16(A + (mb + row) * KD + kb + h * 8, Al + idx * 8);
            gl_lds16(Bt + (nb + row) * KD + kb + h * 8, Bl + idx * 8);
        }
        __syncthreads();
        bf16x8 af[4], bfr[4];
#pragma unroll
        for (int u = 0; u < 4; u++) {
            af[u]  = *(const bf16x8*)(Al + (wm * 64 + u * 16 + l15) * 32 + l4 * 8);
            bfr[u] = *(const bf16x8*)(Bl + (wn * 64 + u * 16 + l15) * 32 + l4 * 8);
        }
#pragma unroll
        for (int am = 0; am < 4; am++)
#pragma unroll
            for (int bn = 0; bn < 4; bn++)
                acc[am][bn] = MFMA16(af[am], bfr[bn], acc[am][bn]);
    }

#pragma unroll
    for (int am = 0; am < 4; am++)
#pragma unroll
        for (int bn = 0; bn < 4; bn++) {
            int n = nb + wn * 64 + bn * 16 + l15;
            int which = n >> 10, hh = (n >> 6) & 15, d = n & 63;
            u16* dst = (which == 0) ? Qo : ((which == 1) ? Ko : Vo);
            float bz = bias[n];
#pragma unroll
            for (int i = 0; i < 4; i++) {
                int m = mb + wm * 64 + am * 16 + l4 * 4 + i;
                int b = m >> 11, t = m & 2047;
                dst[((b * NH + hh) * TSEQ + t) * DH + d] = f2bf(acc[am][bn][i] + bz);
            }
        }
}

// ---------------------------------------------------------------------------
// Out GEMM bf16: Oc[8192][1024] @ Wot[1024][1024]^T + b -> fp32 out
// ---------------------------------------------------------------------------
__global__ __launch_bounds__(256) void out_gemm_bf(
    const u16* __restrict__ A, const u16* __restrict__ Bt,
    const float* __restrict__ bias, float* __restrict__ Out) {
    __shared__ u16 Al[128 * 32];
    __shared__ u16 Bl[128 * 32];
    const int tid = threadIdx.x;
    const int lane = tid & 63, w = tid >> 6;
    const int l15 = lane & 15, l4 = lane >> 4;
    const int wm = w >> 1, wn = w & 1;
    const int mb = blockIdx.y * 128, nb = blockIdx.x * 128;
    const int KD = 1024;

    f32x4 zero = {0.f, 0.f, 0.f, 0.f};
    f32x4 acc[4][4];
#pragma unroll
    for (int i = 0; i < 4; i++)
#pragma unroll
        for (int j = 0; j < 4; j++) acc[i][j] = zero;

    for (int kb = 0; kb < KD; kb += 32) {
        __syncthreads();
#pragma unroll
        for (int r = 0; r < 2; r++) {
            int idx = r * 256 + tid;
            int row = idx >> 2, h = idx & 3;
            gl_lds16(A + (mb + row) * KD + kb + h * 8, Al + idx * 8);
            gl_lds16(Bt + (nb + row) * KD + kb + h * 8, Bl + idx * 8);
        }
        __syncthreads();
        bf16x8 af[4], bfr[4];
#pragma unroll
        for (int u = 0; u < 4; u++) {
            af[u]  = *(const bf16x8*)(Al + (wm * 64 + u * 16 + l15) * 32 + l4 * 8);
            bfr[u] = *(const bf16x8*)(Bl + (wn * 64 + u * 16 + l15) * 32 + l4 * 8);
        }
#pragma unroll
        for (int am = 0; am < 4; am++)
#pragma unroll
            for (int bn = 0; bn < 4; bn++)
                acc[am][bn] = MFMA16(af[am], bfr[bn], acc[am][bn]);
    }

#pragma unroll
    for (int am = 0; am < 4; am++)
#pragma unroll
        for (int bn = 0; bn < 4; bn++) {
            int n = nb + wn * 64 + bn * 16 + l15;
            float bz = bias[n];
#pragma unroll
            for (int i = 0; i < 4; i++) {
                int m = mb + wm * 64 + am * 16 + l4 * 4 + i;
                Out[m * CDIM + n] = acc[am][bn][i] + bz;
            }
        }
}

// ---------------------------------------------------------------------------
// Flash attention bf16 MFMA. Block = (bh, qtile of 64). 4 waves x 16 q-rows.
// K_lds/Vt_lds: [64][64] bf16 staged via global_load_lds with both-sides
// granule swizzle h ^= (row&7) (T2-equivalent, rule 21). P via stride-72 LDS.
// ---------------------------------------------------------------------------
__global__ __launch_bounds__(256) void attn_mfma(
    const u16* __restrict__ Q, const u16* __restrict__ K,
    const u16* __restrict__ Vt, u16* __restrict__ Oc) {
    __shared__ u16 Kl[64 * 64];
    __shared__ u16 Vl[64 * 64];
    __shared__ u16 Pl[4][16][72];

    const int tid = threadIdx.x;
    const int lane = tid & 63, w = tid >> 6;
    const int l15 = lane & 15, l4 = lane >> 4;
    const int qt = blockIdx.x & 31;
    const int bh = blockIdx.x >> 5;

    const u16* Qb = Q + bh * TSEQ * DH;
    const u16* Kb = K + bh * TSEQ * DH;
    const u16* Vb = Vt + bh * DH * TSEQ;

    // Q fragments for this wave's 16 rows (held in regs all kernel)
    bf16x8 qf[2];
    {
        int t = qt * 64 + w * 16 + l15;
        const u16* qp = Qb + t * DH + l4 * 8;
        qf[0] = *(const bf16x8*)(qp);
        qf[1] = *(const bf16x8*)(qp + 32);
    }

    f32x4 zero = {0.f, 0.f, 0.f, 0.f};
    f32x4 oacc[4];
    float m_r[4], l_r[4];
#pragma unroll
    for (int i = 0; i < 4; i++) { oacc[i] = zero; m_r[i] = -INFINITY; l_r[i] = 0.f; }

    for (int kt = 0; kt <= qt; kt++) {
        __syncthreads();  // prior tile's K/V reads complete
#pragma unroll
        for (int r = 0; r < 2; r++) {
            int idx = r * 256 + tid;   // granule: row (64), h (8)
            int row = idx >> 3, h = idx & 7;
            int hs = h ^ (row & 7);    // inverse-swizzled global source
            gl_lds16(Kb + (kt * 64 + row) * DH + hs * 8, Kl + idx * 8);
            gl_lds16(Vb + row * TSEQ + kt * 64 + hs * 8, Vl + idx * 8);
        }
        __syncthreads();

        // S = Q K^T  (per wave: 16 q-rows x 64 k-cols)
        f32x4 sacc[4];
#pragma unroll
        for (int c = 0; c < 4; c++) {
            int trow = c * 16 + l15;
            int sw = trow & 7;
            bf16x8 kf0 = *(const bf16x8*)(Kl + trow * 64 + (l4 ^ sw) * 8);
            bf16x8 kf1 = *(const bf16x8*)(Kl + trow * 64 + ((4 + l4) ^ sw) * 8);
            f32x4 a = zero;
            a = MFMA16(qf[0], kf0, a);
            a = MFMA16(qf[1], kf1, a);
            sacc[c] = a;
        }

        float s[4][4];
#pragma unroll
        for (int c = 0; c < 4; c++)
#pragma unroll
            for (int i = 0; i < 4; i++) s[c][i] = sacc[c][i] * 0.125f;

        if (kt == qt) {
#pragma unroll
            for (int c = 0; c < 4; c++)
#pragma unroll
                for (int i = 0; i < 4; i++)
                    if (c * 16 + l15 > w * 16 + l4 * 4 + i) s[c][i] = -INFINITY;
        }

        // online softmax (rows live across 16-lane groups)
        float p[4][4];
#pragma unroll
        for (int i = 0; i < 4; i++) {
            float tm = fmaxf(fmaxf(s[0][i], s[1][i]), fmaxf(s[2][i], s[3][i]));
            tm = fmaxf(tm, __shfl_xor(tm, 1));
            tm = fmaxf(tm, __shfl_xor(tm, 2));
            tm = fmaxf(tm, __shfl_xor(tm, 4));
            tm = fmaxf(tm, __shfl_xor(tm, 8));
            float mnew = fmaxf(m_r[i], tm);
            float corr = __expf(m_r[i] - mnew);
            float rs = 0.f;
#pragma unroll
            for (int c = 0; c < 4; c++) { p[c][i] = __expf(s[c][i] - mnew); rs += p[c][i]; }
            rs += __shfl_xor(rs, 1);
            rs += __shfl_xor(rs, 2);
            rs += __shfl_xor(rs, 4);
            rs += __shfl_xor(rs, 8);
            l_r[i] = l_r[i] * corr + rs;
            m_r[i] = mnew;
#pragma unroll
            for (int dg = 0; dg < 4; dg++) oacc[dg][i] *= corr;
        }

        // P -> LDS (bf16, per-wave region)
#pragma unroll
        for (int c = 0; c < 4; c++)
#pragma unroll
            for (int i = 0; i < 4; i++)
                Pl[w][l4 * 4 + i][c * 16 + l15] = f2bf(p[c][i]);
        __syncthreads();  // P visible + all waves done with Kl before next stage

        // O += P V  (A = P rows, B = Vt cols)
#pragma unroll
        for (int kk = 0; kk < 2; kk++) {
            bf16x8 pf = *(const bf16x8*)(&Pl[w][l15][kk * 32 + l4 * 8]);
#pragma unroll
            for (int dg = 0; dg < 4; dg++) {
                int drow = dg * 16 + l15;
                int h = (kk * 4 + l4) ^ (drow & 7);
                bf16x8 vf = *(const bf16x8*)(Vl + drow * 64 + h * 8);
                oacc[dg] = MFMA16(pf, vf, oacc[dg]);
            }
        }
    }

    // epilogue: normalize + write concat (B,T,C) bf16
    const int b = bh >> 4, hh = bh & 15;
#pragma unroll
    for (int i = 0; i < 4; i++) {
        float inv = 1.0f / l_r[i];
        int t = qt * 64 + w * 16 + l4 * 4 + i;
#pragma unroll
        for (int dg = 0; dg < 4; dg++)
            Oc[(b * TSEQ + t) * CDIM + hh * DH + dg * 16 + l15] = f2bf(oacc[dg][i] * inv);
    }
}

extern "C" void kernel_launch(void* const* d_in, const int* in_sizes, int n_in,
                              void* d_out, int out_size, void* d_ws, size_t ws_size,
                              hipStream_t stream) {
    const float* x     = (const float*)d_in[0];
    const float* W_qkv = (const float*)d_in[1];
    const float* b_qkv = (const float*)d_in[2];
    const float* W_out = (const float*)d_in[3];
    const float* b_out = (const float*)d_in[4];
    float* out = (float*)d_out;

    // ws layout (u16 elements), total ~104 MB
    u16* xb  = (u16*)d_ws;            // 8192*1024
    u16* Wqt = xb  + 8388608;         // 3072*1024
    u16* Wot = Wqt + 3145728;         // 1024*1024
    u16* Qw  = Wot + 1048576;         // 64*2048*64
    u16* Kw  = Qw  + 8388608;
    u16* Vw  = Kw  + 8388608;
    u16* Vtw = Vw  + 8388608;
    u16* Ocw = Vtw + 8388608;

    cvt_bf16<<<4096, 256, 0, stream>>>(x, xb, 8388608);
    tr_w_bf16<<<dim3(96, 32), dim3(32, 8), 0, stream>>>(W_qkv, Wqt, 1024, 3072);
    tr_w_bf16<<<dim3(32, 32), dim3(32, 8), 0, stream>>>(W_out, Wot, 1024, 1024);
    qkv_gemm_bf<<<dim3(24, 64), 256, 0, stream>>>(xb, Wqt, b_qkv, Qw, Kw, Vw);
    tr_v_bf16<<<dim3(32, 64), 256, 0, stream>>>(Vw, Vtw);
    attn_mfma<<<2048, 256, 0, stream>>>(Qw, Kw, Vtw, Ocw);
    out_gemm_bf<<<dim3(8, 64), 256, 0, stream>>>(Ocw, Wot, b_out, out);
}

// Round 3
// 273.747 us; speedup vs baseline: 7.0395x; 1.4920x over previous
//
#include <hip/hip_runtime.h>
#include <math.h>

typedef __attribute__((ext_vector_type(8))) short bf16x8;
typedef __attribute__((ext_vector_type(4))) float f32x4;
typedef unsigned short u16;
typedef unsigned int u32;

#define TSEQ 2048
#define NH   16
#define DH   64
#define CDIM 1024

__device__ __forceinline__ u16 f2bf(float f) {
    union { float f; u32 u; } v; v.f = f;
    u32 r = v.u + 0x7fffu + ((v.u >> 16) & 1u);
    return (u16)(r >> 16);
}

__device__ __forceinline__ void gl_lds16(const void* g, void* l) {
    __builtin_amdgcn_global_load_lds(
        (const __attribute__((address_space(1))) u32*)g,
        (__attribute__((address_space(3))) u32*)l, 16, 0, 0);
}

#define MFMA16(a, b, c) __builtin_amdgcn_mfma_f32_16x16x32_bf16(a, b, c, 0, 0, 0)

// ---------------------------------------------------------------------------
// fp32 -> bf16 elementwise (x)
// ---------------------------------------------------------------------------
__global__ __launch_bounds__(256) void cvt_bf16(const float* __restrict__ in,
                                                u16* __restrict__ out, int n) {
    int i = (blockIdx.x * 256 + threadIdx.x) * 8;
    if (i >= n) return;
    float4 a = *(const float4*)(in + i);
    float4 b = *(const float4*)(in + i + 4);
    u16 o[8] = {f2bf(a.x), f2bf(a.y), f2bf(a.z), f2bf(a.w),
                f2bf(b.x), f2bf(b.y), f2bf(b.z), f2bf(b.w)};
    *(uint4*)(out + i) = *(const uint4*)o;
}

// ---------------------------------------------------------------------------
// fp32 W[K][N] -> bf16 Wt[N][K]  (32x32 tiles, block (32,8))
// ---------------------------------------------------------------------------
__global__ __launch_bounds__(256) void tr_w_bf16(const float* __restrict__ Wf,
                                                 u16* __restrict__ Wt, int K, int N) {
    __shared__ float tile[32][33];
    int n0 = blockIdx.x * 32, k0 = blockIdx.y * 32;
    int tx = threadIdx.x, ty = threadIdx.y;
#pragma unroll
    for (int r = 0; r < 4; r++)
        tile[ty + r * 8][tx] = Wf[(k0 + ty + r * 8) * N + n0 + tx];
    __syncthreads();
#pragma unroll
    for (int r = 0; r < 4; r++)
        Wt[(n0 + ty + r * 8) * K + k0 + tx] = f2bf(tile[tx][ty + r * 8]);
}

// ---------------------------------------------------------------------------
// bf16 V[bh][T][Dh] -> bf16 Vt[bh][Dh][T]  (64x64 tiles)
// ---------------------------------------------------------------------------
__global__ __launch_bounds__(256) void tr_v_bf16(const u16* __restrict__ V,
                                                 u16* __restrict__ Vt) {
    __shared__ u16 Vl[64][72];
    const int tt = blockIdx.x, bh = blockIdx.y;
    const u16* src = V + (bh * TSEQ + tt * 64) * DH;
    const int tid = threadIdx.x;
#pragma unroll
    for (int r = 0; r < 2; r++) {
        int idx = r * 256 + tid;
        int row = idx >> 3, h = idx & 7;
        uint4 d4 = *(const uint4*)(src + row * DH + h * 8);
        *(uint4*)(&Vl[row][h * 8]) = d4;
    }
    __syncthreads();
    u16* dstb = Vt + bh * DH * TSEQ + tt * 64;
#pragma unroll
    for (int r = 0; r < 2; r++) {
        int idx = r * 256 + tid;
        int d = idx >> 3, ht = idx & 7;
        u16 o[8];
#pragma unroll
        for (int e = 0; e < 8; e++) o[e] = Vl[ht * 8 + e][d];
        *(uint4*)(dstb + d * TSEQ + ht * 8) = *(const uint4*)o;
    }
}

// ---------------------------------------------------------------------------
// QKV GEMM bf16 (m97 structure, unchanged from round 2)
// ---------------------------------------------------------------------------
__global__ __launch_bounds__(256) void qkv_gemm_bf(
    const u16* __restrict__ A, const u16* __restrict__ Bt,
    const float* __restrict__ bias,
    u16* __restrict__ Qo, u16* __restrict__ Ko, u16* __restrict__ Vo) {
    __shared__ u16 Al[128 * 32];
    __shared__ u16 Bl[128 * 32];
    const int tid = threadIdx.x;
    const int lane = tid & 63, w = tid >> 6;
    const int l15 = lane & 15, l4 = lane >> 4;
    const int wm = w >> 1, wn = w & 1;
    const int mb = blockIdx.y * 128, nb = blockIdx.x * 128;
    const int KD = 1024;

    f32x4 zero = {0.f, 0.f, 0.f, 0.f};
    f32x4 acc[4][4];
#pragma unroll
    for (int i = 0; i < 4; i++)
#pragma unroll
        for (int j = 0; j < 4; j++) acc[i][j] = zero;

    for (int kb = 0; kb < KD; kb += 32) {
        __syncthreads();
#pragma unroll
        for (int r = 0; r < 2; r++) {
            int idx = r * 256 + tid;
            int row = idx >> 2, h = idx & 3;
            gl_lds16(A + (mb + row) * KD + kb + h * 8, Al + idx * 8);
            gl_lds16(Bt + (nb + row) * KD + kb + h * 8, Bl + idx * 8);
        }
        __syncthreads();
        bf16x8 af[4], bfr[4];
#pragma unroll
        for (int u = 0; u < 4; u++) {
            af[u]  = *(const bf16x8*)(Al + (wm * 64 + u * 16 + l15) * 32 + l4 * 8);
            bfr[u] = *(const bf16x8*)(Bl + (wn * 64 + u * 16 + l15) * 32 + l4 * 8);
        }
#pragma unroll
        for (int am = 0; am < 4; am++)
#pragma unroll
            for (int bn = 0; bn < 4; bn++)
                acc[am][bn] = MFMA16(af[am], bfr[bn], acc[am][bn]);
    }

#pragma unroll
    for (int am = 0; am < 4; am++)
#pragma unroll
        for (int bn = 0; bn < 4; bn++) {
            int n = nb + wn * 64 + bn * 16 + l15;
            int which = n >> 10, hh = (n >> 6) & 15, d = n & 63;
            u16* dst = (which == 0) ? Qo : ((which == 1) ? Ko : Vo);
            float bz = bias[n];
#pragma unroll
            for (int i = 0; i < 4; i++) {
                int m = mb + wm * 64 + am * 16 + l4 * 4 + i;
                int b = m >> 11, t = m & 2047;
                dst[((b * NH + hh) * TSEQ + t) * DH + d] = f2bf(acc[am][bn][i] + bz);
            }
        }
}

// ---------------------------------------------------------------------------
// Out GEMM bf16 (unchanged)
// ---------------------------------------------------------------------------
__global__ __launch_bounds__(256) void out_gemm_bf(
    const u16* __restrict__ A, const u16* __restrict__ Bt,
    const float* __restrict__ bias, float* __restrict__ Out) {
    __shared__ u16 Al[128 * 32];
    __shared__ u16 Bl[128 * 32];
    const int tid = threadIdx.x;
    const int lane = tid & 63, w = tid >> 6;
    const int l15 = lane & 15, l4 = lane >> 4;
    const int wm = w >> 1, wn = w & 1;
    const int mb = blockIdx.y * 128, nb = blockIdx.x * 128;
    const int KD = 1024;

    f32x4 zero = {0.f, 0.f, 0.f, 0.f};
    f32x4 acc[4][4];
#pragma unroll
    for (int i = 0; i < 4; i++)
#pragma unroll
        for (int j = 0; j < 4; j++) acc[i][j] = zero;

    for (int kb = 0; kb < KD; kb += 32) {
        __syncthreads();
#pragma unroll
        for (int r = 0; r < 2; r++) {
            int idx = r * 256 + tid;
            int row = idx >> 2, h = idx & 3;
            gl_lds16(A + (mb + row) * KD + kb + h * 8, Al + idx * 8);
            gl_lds16(Bt + (nb + row) * KD + kb + h * 8, Bl + idx * 8);
        }
        __syncthreads();
        bf16x8 af[4], bfr[4];
#pragma unroll
        for (int u = 0; u < 4; u++) {
            af[u]  = *(const bf16x8*)(Al + (wm * 64 + u * 16 + l15) * 32 + l4 * 8);
            bfr[u] = *(const bf16x8*)(Bl + (wn * 64 + u * 16 + l15) * 32 + l4 * 8);
        }
#pragma unroll
        for (int am = 0; am < 4; am++)
#pragma unroll
            for (int bn = 0; bn < 4; bn++)
                acc[am][bn] = MFMA16(af[am], bfr[bn], acc[am][bn]);
    }

#pragma unroll
    for (int am = 0; am < 4; am++)
#pragma unroll
        for (int bn = 0; bn < 4; bn++) {
            int n = nb + wn * 64 + bn * 16 + l15;
            float bz = bias[n];
#pragma unroll
            for (int i = 0; i < 4; i++) {
                int m = mb + wm * 64 + am * 16 + l4 * 4 + i;
                Out[m * CDIM + n] = acc[am][bn][i] + bz;
            }
        }
}

// ---------------------------------------------------------------------------
// Flash attention v3: pair-balanced blocks, double-buffered K/V with counted
// vmcnt, swapped QK^T (S^T: q = lane&15), per-wave swizzled P buffer.
// Block = (bh, pair): q-tiles {pair, 31-pair} sequentially; 33 steps uniform.
// LDS = 2*8K(K) + 2*8K(V) + 8K(P) = 40960 B -> 4 blocks/CU.
// ---------------------------------------------------------------------------
__global__ __launch_bounds__(256, 4) void attn_mfma(
    const u16* __restrict__ Q, const u16* __restrict__ K,
    const u16* __restrict__ Vt, u16* __restrict__ Oc) {
    __shared__ u16 Kl[2][4096];
    __shared__ u16 Vl[2][4096];
    __shared__ u16 Pl[4096];   // 4 waves x [16][64], XOR-swizzled

    const int tid = threadIdx.x;
    const int lane = tid & 63, w = tid >> 6;
    const int l15 = lane & 15, l4 = lane >> 4;
    const int bh = blockIdx.x & 63;
    const int pair = blockIdx.x >> 6;
    const int qt0 = pair, qt1 = 31 - pair;
    const int nt0 = qt0 + 1;
    const int ntt = 33;  // nt0 + (qt1+1)

    const u16* Qb = Q + bh * TSEQ * DH;
    const u16* Kb = K + bh * TSEQ * DH;
    const u16* Vb = Vt + bh * DH * TSEQ;

    const int srow = tid >> 3;        // 0..63 (stage: covers 64 rows over 2 r-iters? no: 512 idx)
    const float SCL = 0.18033688011112042f;  // 0.125 * log2(e)

    auto STAGE = [&](int kt, int p) {
#pragma unroll
        for (int r = 0; r < 2; r++) {
            int idx = r * 256 + tid;
            int row = idx >> 3, h = idx & 7;
            int hs = h ^ (row & 7);
            gl_lds16(Kb + (kt * 64 + row) * DH + hs * 8, &Kl[p][idx * 8]);
            gl_lds16(Vb + row * TSEQ + kt * 64 + hs * 8, &Vl[p][idx * 8]);
        }
    };

    STAGE(0, 0);

    int sg = 0;
    const int b = bh >> 4, hh = bh & 15;

    for (int half = 0; half < 2; half++) {
        const int qt = half ? qt1 : qt0;
        const int q_row = qt * 64 + w * 16 + l15;

        // Q fragments (b-operand: col=q=l15, k=d)
        bf16x8 qf0, qf1;
        {
            const u16* qp = Qb + q_row * DH + l4 * 8;
            qf0 = *(const bf16x8*)(qp);
            qf1 = *(const bf16x8*)(qp + 32);
        }

        f32x4 zero = {0.f, 0.f, 0.f, 0.f};
        f32x4 oacc[4];
        float m_r = -INFINITY, l_r = 0.f;
#pragma unroll
        for (int i = 0; i < 4; i++) oacc[i] = zero;

        for (int kt = 0; kt <= qt; kt++, sg++) {
            const int p = sg & 1;
            __syncthreads();  // all waves done reading buf p^1 (step sg-1)
            int ns = sg + 1;
            if (ns < ntt) {
                int nkt = (ns < nt0) ? ns : (ns - nt0);
                STAGE(nkt, p ^ 1);
                asm volatile("s_waitcnt vmcnt(4)" ::: "memory");
            } else {
                asm volatile("s_waitcnt vmcnt(0)" ::: "memory");
            }
            __syncthreads();  // step-sg data landed for all waves

            // S^T = K Q^T : rows k_local = c*16 + l4*4 + r, col q = l15
            __builtin_amdgcn_s_setprio(1);
            f32x4 sacc[4];
#pragma unroll
            for (int c = 0; c < 4; c++) {
                int trow = c * 16 + l15;
                int sw = l15 & 7;
                bf16x8 kf0 = *(const bf16x8*)(&Kl[p][trow * 64 + (l4 ^ sw) * 8]);
                bf16x8 kf1 = *(const bf16x8*)(&Kl[p][trow * 64 + ((4 + l4) ^ sw) * 8]);
                f32x4 a = zero;
                a = MFMA16(kf0, qf0, a);
                a = MFMA16(kf1, qf1, a);
                sacc[c] = a;
            }
            __builtin_amdgcn_s_setprio(0);

            if (kt == qt) {
#pragma unroll
                for (int c = 0; c < 4; c++)
#pragma unroll
                    for (int i = 0; i < 4; i++) {
                        int kg = kt * 64 + c * 16 + l4 * 4 + i;
                        if (kg > q_row) sacc[c][i] = -INFINITY;
                    }
            }

            // softmax over k (16 in-lane + lanes l4): 2 shfl rounds
            float mx = sacc[0][0];
#pragma unroll
            for (int c = 0; c < 4; c++)
#pragma unroll
                for (int i = 0; i < 4; i++) mx = fmaxf(mx, sacc[c][i]);
            mx = fmaxf(mx, __shfl_xor(mx, 16));
            mx = fmaxf(mx, __shfl_xor(mx, 32));
            float mnew = fmaxf(m_r, mx);
            float corr = __builtin_amdgcn_exp2f((m_r - mnew) * SCL);

            float pv[16];
            float rs = 0.f;
#pragma unroll
            for (int c = 0; c < 4; c++)
#pragma unroll
                for (int i = 0; i < 4; i++) {
                    float e = __builtin_amdgcn_exp2f((sacc[c][i] - mnew) * SCL);
                    pv[c * 4 + i] = e;
                    rs += e;
                }
            rs += __shfl_xor(rs, 16);
            rs += __shfl_xor(rs, 32);
            l_r = l_r * corr + rs;
            m_r = mnew;

            // P -> per-wave swizzled LDS (no cross-wave barrier needed)
#pragma unroll
            for (int c = 0; c < 4; c++) {
                u16 po[4];
#pragma unroll
                for (int i = 0; i < 4; i++) po[i] = f2bf(pv[c * 4 + i]);
                int g = (c << 1) + (l4 >> 1);
                int gp = g ^ (l15 & 7);
                *(uint2*)&Pl[w * 1024 + l15 * 64 + gp * 8 + ((l4 & 1) << 2)] =
                    *(const uint2*)po;
            }

            // rescale O (rows q = l4*4+r in C-layout)
            float cr[4];
#pragma unroll
            for (int r = 0; r < 4; r++) cr[r] = __shfl(corr, l4 * 4 + r);
#pragma unroll
            for (int dg = 0; dg < 4; dg++)
#pragma unroll
                for (int r = 0; r < 4; r++) oacc[dg][r] *= cr[r];

            // O += P V  (A = P rows q, B = Vt d-cols)
            __builtin_amdgcn_s_setprio(1);
#pragma unroll
            for (int kk = 0; kk < 2; kk++) {
                int grp = ((kk << 2) + l4) ^ (l15 & 7);
                bf16x8 pf = *(const bf16x8*)&Pl[w * 1024 + l15 * 64 + grp * 8];
#pragma unroll
                for (int dg = 0; dg < 4; dg++) {
                    int drow = (dg << 4) + l15;
                    bf16x8 vf = *(const bf16x8*)(&Vl[p][drow * 64 + grp * 8]);
                    oacc[dg] = MFMA16(pf, vf, oacc[dg]);
                }
            }
            __builtin_amdgcn_s_setprio(0);
        }

        // epilogue for this half
        float inv[4];
#pragma unroll
        for (int r = 0; r < 4; r++) inv[r] = 1.0f / __shfl(l_r, l4 * 4 + r);
        int tbase = qt * 64 + w * 16 + l4 * 4;
#pragma unroll
        for (int r = 0; r < 4; r++) {
            int t = tbase + r;
#pragma unroll
            for (int dg = 0; dg < 4; dg++)
                Oc[(b * TSEQ + t) * CDIM + hh * DH + (dg << 4) + l15] =
                    f2bf(oacc[dg][r] * inv[r]);
        }
    }
}

extern "C" void kernel_launch(void* const* d_in, const int* in_sizes, int n_in,
                              void* d_out, int out_size, void* d_ws, size_t ws_size,
                              hipStream_t stream) {
    const float* x     = (const float*)d_in[0];
    const float* W_qkv = (const float*)d_in[1];
    const float* b_qkv = (const float*)d_in[2];
    const float* W_out = (const float*)d_in[3];
    const float* b_out = (const float*)d_in[4];
    float* out = (float*)d_out;

    u16* xb  = (u16*)d_ws;            // 8192*1024
    u16* Wqt = xb  + 8388608;         // 3072*1024
    u16* Wot = Wqt + 3145728;         // 1024*1024
    u16* Qw  = Wot + 1048576;         // 64*2048*64
    u16* Kw  = Qw  + 8388608;
    u16* Vw  = Kw  + 8388608;
    u16* Vtw = Vw  + 8388608;
    u16* Ocw = Vtw + 8388608;

    cvt_bf16<<<4096, 256, 0, stream>>>(x, xb, 8388608);
    tr_w_bf16<<<dim3(96, 32), dim3(32, 8), 0, stream>>>(W_qkv, Wqt, 1024, 3072);
    tr_w_bf16<<<dim3(32, 32), dim3(32, 8), 0, stream>>>(W_out, Wot, 1024, 1024);
    qkv_gemm_bf<<<dim3(24, 64), 256, 0, stream>>>(xb, Wqt, b_qkv, Qw, Kw, Vw);
    tr_v_bf16<<<dim3(32, 64), 256, 0, stream>>>(Vw, Vtw);
    attn_mfma<<<1024, 256, 0, stream>>>(Qw, Kw, Vtw, Ocw);
    out_gemm_bf<<<dim3(8, 64), 256, 0, stream>>>(Ocw, Wot, b_out, out);
}

// Round 4
// 271.921 us; speedup vs baseline: 7.0867x; 1.0067x over previous
//
#include <hip/hip_runtime.h>
#include <math.h>

typedef __attribute__((ext_vector_type(8))) short bf16x8;
typedef __attribute__((ext_vector_type(4))) float f32x4;
typedef unsigned short u16;
typedef unsigned int u32;

#define TSEQ 2048
#define NH   16
#define DH   64
#define CDIM 1024
#define SCLQ 0.18033688011112042f  // 0.125 * log2(e): folded into Q

__device__ __forceinline__ u16 f2bf(float f) {
    union { float f; u32 u; } v; v.f = f;
    u32 r = v.u + 0x7fffu + ((v.u >> 16) & 1u);
    return (u16)(r >> 16);
}

__device__ __forceinline__ u32 cvtpk(float lo, float hi) {
    u32 r;
    asm("v_cvt_pk_bf16_f32 %0, %1, %2" : "=v"(r) : "v"(lo), "v"(hi));
    return r;
}

__device__ __forceinline__ float max3f(float a, float b, float c) {
    return fmaxf(fmaxf(a, b), c);  // fuses to v_max3_f32
}

__device__ __forceinline__ void gl_lds16(const void* g, void* l) {
    __builtin_amdgcn_global_load_lds(
        (const __attribute__((address_space(1))) u32*)g,
        (__attribute__((address_space(3))) u32*)l, 16, 0, 0);
}

#define MFMA16(a, b, c) __builtin_amdgcn_mfma_f32_16x16x32_bf16(a, b, c, 0, 0, 0)

// ---------------------------------------------------------------------------
// fp32 -> bf16 elementwise (x)
// ---------------------------------------------------------------------------
__global__ __launch_bounds__(256) void cvt_bf16(const float* __restrict__ in,
                                                u16* __restrict__ out, int n) {
    int i = (blockIdx.x * 256 + threadIdx.x) * 8;
    if (i >= n) return;
    float4 a = *(const float4*)(in + i);
    float4 b = *(const float4*)(in + i + 4);
    u16 o[8] = {f2bf(a.x), f2bf(a.y), f2bf(a.z), f2bf(a.w),
                f2bf(b.x), f2bf(b.y), f2bf(b.z), f2bf(b.w)};
    *(uint4*)(out + i) = *(const uint4*)o;
}

// ---------------------------------------------------------------------------
// fp32 W[K][N] -> bf16 Wt[N][K]  (32x32 tiles, block (32,8))
// ---------------------------------------------------------------------------
__global__ __launch_bounds__(256) void tr_w_bf16(const float* __restrict__ Wf,
                                                 u16* __restrict__ Wt, int K, int N) {
    __shared__ float tile[32][33];
    int n0 = blockIdx.x * 32, k0 = blockIdx.y * 32;
    int tx = threadIdx.x, ty = threadIdx.y;
#pragma unroll
    for (int r = 0; r < 4; r++)
        tile[ty + r * 8][tx] = Wf[(k0 + ty + r * 8) * N + n0 + tx];
    __syncthreads();
#pragma unroll
    for (int r = 0; r < 4; r++)
        Wt[(n0 + ty + r * 8) * K + k0 + tx] = f2bf(tile[tx][ty + r * 8]);
}

// ---------------------------------------------------------------------------
// QKV GEMM bf16 (m97 structure). Writes Q pre-scaled by SCLQ, K normal,
// V directly transposed to [bh][d][t] (kills the tr_v kernel).
// ---------------------------------------------------------------------------
__global__ __launch_bounds__(256) void qkv_gemm_bf(
    const u16* __restrict__ A, const u16* __restrict__ Bt,
    const float* __restrict__ bias,
    u16* __restrict__ Qo, u16* __restrict__ Ko, u16* __restrict__ Vo) {
    __shared__ u16 Al[128 * 32];
    __shared__ u16 Bl[128 * 32];
    const int tid = threadIdx.x;
    const int lane = tid & 63, w = tid >> 6;
    const int l15 = lane & 15, l4 = lane >> 4;
    const int wm = w >> 1, wn = w & 1;
    const int mb = blockIdx.y * 128, nb = blockIdx.x * 128;
    const int KD = 1024;

    f32x4 zero = {0.f, 0.f, 0.f, 0.f};
    f32x4 acc[4][4];
#pragma unroll
    for (int i = 0; i < 4; i++)
#pragma unroll
        for (int j = 0; j < 4; j++) acc[i][j] = zero;

    for (int kb = 0; kb < KD; kb += 32) {
        __syncthreads();
#pragma unroll
        for (int r = 0; r < 2; r++) {
            int idx = r * 256 + tid;
            int row = idx >> 2, h = idx & 3;
            gl_lds16(A + (mb + row) * KD + kb + h * 8, Al + idx * 8);
            gl_lds16(Bt + (nb + row) * KD + kb + h * 8, Bl + idx * 8);
        }
        __syncthreads();
        bf16x8 af[4], bfr[4];
#pragma unroll
        for (int u = 0; u < 4; u++) {
            af[u]  = *(const bf16x8*)(Al + (wm * 64 + u * 16 + l15) * 32 + l4 * 8);
            bfr[u] = *(const bf16x8*)(Bl + (wn * 64 + u * 16 + l15) * 32 + l4 * 8);
        }
#pragma unroll
        for (int am = 0; am < 4; am++)
#pragma unroll
            for (int bn = 0; bn < 4; bn++)
                acc[am][bn] = MFMA16(af[am], bfr[bn], acc[am][bn]);
    }

#pragma unroll
    for (int am = 0; am < 4; am++)
#pragma unroll
        for (int bn = 0; bn < 4; bn++) {
            int n = nb + wn * 64 + bn * 16 + l15;
            int which = n >> 10, hh = (n >> 6) & 15, d = n & 63;
            float bz = bias[n];
            int m0 = mb + wm * 64 + am * 16 + l4 * 4;
            int b = m0 >> 11, t0 = m0 & 2047;
            if (which == 0) {
#pragma unroll
                for (int i = 0; i < 4; i++)
                    Qo[((b * NH + hh) * TSEQ + t0 + i) * DH + d] =
                        f2bf((acc[am][bn][i] + bz) * SCLQ);
            } else if (which == 1) {
#pragma unroll
                for (int i = 0; i < 4; i++)
                    Ko[((b * NH + hh) * TSEQ + t0 + i) * DH + d] =
                        f2bf(acc[am][bn][i] + bz);
            } else {
                u16 ov[4];
#pragma unroll
                for (int i = 0; i < 4; i++) ov[i] = f2bf(acc[am][bn][i] + bz);
                *(uint2*)&Vo[((b * NH + hh) * DH + d) * TSEQ + t0] =
                    *(const uint2*)ov;
            }
        }
}

// ---------------------------------------------------------------------------
// Out GEMM bf16 (unchanged)
// ---------------------------------------------------------------------------
__global__ __launch_bounds__(256) void out_gemm_bf(
    const u16* __restrict__ A, const u16* __restrict__ Bt,
    const float* __restrict__ bias, float* __restrict__ Out) {
    __shared__ u16 Al[128 * 32];
    __shared__ u16 Bl[128 * 32];
    const int tid = threadIdx.x;
    const int lane = tid & 63, w = tid >> 6;
    const int l15 = lane & 15, l4 = lane >> 4;
    const int wm = w >> 1, wn = w & 1;
    const int mb = blockIdx.y * 128, nb = blockIdx.x * 128;
    const int KD = 1024;

    f32x4 zero = {0.f, 0.f, 0.f, 0.f};
    f32x4 acc[4][4];
#pragma unroll
    for (int i = 0; i < 4; i++)
#pragma unroll
        for (int j = 0; j < 4; j++) acc[i][j] = zero;

    for (int kb = 0; kb < KD; kb += 32) {
        __syncthreads();
#pragma unroll
        for (int r = 0; r < 2; r++) {
            int idx = r * 256 + tid;
            int row = idx >> 2, h = idx & 3;
            gl_lds16(A + (mb + row) * KD + kb + h * 8, Al + idx * 8);
            gl_lds16(Bt + (nb + row) * KD + kb + h * 8, Bl + idx * 8);
        }
        __syncthreads();
        bf16x8 af[4], bfr[4];
#pragma unroll
        for (int u = 0; u < 4; u++) {
            af[u]  = *(const bf16x8*)(Al + (wm * 64 + u * 16 + l15) * 32 + l4 * 8);
            bfr[u] = *(const bf16x8*)(Bl + (wn * 64 + u * 16 + l15) * 32 + l4 * 8);
        }
#pragma unroll
        for (int am = 0; am < 4; am++)
#pragma unroll
            for (int bn = 0; bn < 4; bn++)
                acc[am][bn] = MFMA16(af[am], bfr[bn], acc[am][bn]);
    }

#pragma unroll
    for (int am = 0; am < 4; am++)
#pragma unroll
        for (int bn = 0; bn < 4; bn++) {
            int n = nb + wn * 64 + bn * 16 + l15;
            float bz = bias[n];
#pragma unroll
            for (int i = 0; i < 4; i++) {
                int m = mb + wm * 64 + am * 16 + l4 * 4 + i;
                Out[m * CDIM + n] = acc[am][bn][i] + bz;
            }
        }
}

// ---------------------------------------------------------------------------
// Flash attention v4: JOINT pair processing. Block = (bh, pair p): q-tiles
// qt0=p and qt1=31-p processed concurrently over kt=0..qt1 (32-p steps,
// exactly 33 compute units per block). One K/V stage serves both halves;
// K fragments feed 16 S-MFMAs. Double-buffered K/V, counted vmcnt(4).
// Scores arrive pre-scaled (Q folded) -> exp2 directly. Exact skip-rescale.
// LDS = 16K(K) + 16K(V) + 8K(P) = 40960 B -> 4 blocks/CU (grid 1024 = all
// resident, one round).
// ---------------------------------------------------------------------------
__global__ __launch_bounds__(256, 4) void attn_mfma(
    const u16* __restrict__ Q, const u16* __restrict__ K,
    const u16* __restrict__ Vt, u16* __restrict__ Oc) {
    __shared__ u16 Kl[2][4096];
    __shared__ u16 Vl[2][4096];
    __shared__ u16 Pl[4096];   // 4 waves x [16][64] u16, XOR-swizzled; shared by halves

    const int tid = threadIdx.x;
    const int lane = tid & 63, w = tid >> 6;
    const int l15 = lane & 15, l4 = lane >> 4;
    const int bh = blockIdx.x & 63;
    const int pair = blockIdx.x >> 6;       // 0..15
    const int qt0 = pair, qt1 = 31 - pair;
    const int NT = qt1 + 1;

    const u16* Qb = Q + bh * TSEQ * DH;
    const u16* Kb = K + bh * TSEQ * DH;
    const u16* Vb = Vt + bh * DH * TSEQ;

    auto STAGE = [&](int kt, int p) {
#pragma unroll
        for (int r = 0; r < 2; r++) {
            int idx = r * 256 + tid;
            int row = idx >> 3, h = idx & 7;
            int hs = h ^ (row & 7);
            gl_lds16(Kb + (kt * 64 + row) * DH + hs * 8, &Kl[p][idx * 8]);
            gl_lds16(Vb + row * TSEQ + kt * 64 + hs * 8, &Vl[p][idx * 8]);
        }
    };

    // Q fragments, both halves (scores come out pre-scaled by SCLQ)
    const int qrow0 = qt0 * 64 + w * 16 + l15;
    const int qrow1 = qt1 * 64 + w * 16 + l15;
    bf16x8 q0a, q0b, q1a, q1b;
    {
        const u16* qp = Qb + qrow0 * DH + l4 * 8;
        q0a = *(const bf16x8*)(qp);
        q0b = *(const bf16x8*)(qp + 32);
    }
    {
        const u16* qp = Qb + qrow1 * DH + l4 * 8;
        q1a = *(const bf16x8*)(qp);
        q1b = *(const bf16x8*)(qp + 32);
    }

    f32x4 zero = {0.f, 0.f, 0.f, 0.f};
    f32x4 o0[4], o1[4];
    float m0 = -INFINITY, l0 = 0.f, m1 = -INFINITY, l1 = 0.f;
#pragma unroll
    for (int i = 0; i < 4; i++) { o0[i] = zero; o1[i] = zero; }

    // softmax + PV for one half (s in exp2 domain already)
    auto SMPV = [&](f32x4* s, float& m_r, float& l_r, f32x4* oacc,
                    int q_row, bool domask, int kt, int p) {
        if (domask) {
#pragma unroll
            for (int c = 0; c < 4; c++)
#pragma unroll
                for (int i = 0; i < 4; i++) {
                    int kg = kt * 64 + c * 16 + l4 * 4 + i;
                    if (kg > q_row) s[c][i] = -INFINITY;
                }
        }
        // row max: max3 tree + 2 shfl
        float a0 = max3f(s[0][0], s[0][1], s[0][2]);
        float a1 = max3f(s[0][3], s[1][0], s[1][1]);
        float a2 = max3f(s[1][2], s[1][3], s[2][0]);
        float a3 = max3f(s[2][1], s[2][2], s[2][3]);
        float a4 = max3f(s[3][0], s[3][1], s[3][2]);
        float mx = max3f(max3f(a0, a1, a2), fmaxf(a3, a4), s[3][3]);
        mx = fmaxf(mx, __shfl_xor(mx, 16));
        mx = fmaxf(mx, __shfl_xor(mx, 32));
        if (!__all(mx <= m_r)) {   // exact: skipped only when corr==1 anyway
            float mnew = fmaxf(m_r, mx);
            float corr = __builtin_amdgcn_exp2f(m_r - mnew);
            l_r *= corr;
            float cr[4];
#pragma unroll
            for (int r = 0; r < 4; r++) cr[r] = __shfl(corr, l4 * 4 + r);
#pragma unroll
            for (int dg = 0; dg < 4; dg++)
#pragma unroll
                for (int r = 0; r < 4; r++) oacc[dg][r] *= cr[r];
            m_r = mnew;
        }
        float pv[16];
#pragma unroll
        for (int c = 0; c < 4; c++)
#pragma unroll
            for (int i = 0; i < 4; i++)
                pv[c * 4 + i] = __builtin_amdgcn_exp2f(s[c][i] - m_r);
        float t0 = (pv[0] + pv[1]) + (pv[2] + pv[3]);
        float t1 = (pv[4] + pv[5]) + (pv[6] + pv[7]);
        float t2 = (pv[8] + pv[9]) + (pv[10] + pv[11]);
        float t3 = (pv[12] + pv[13]) + (pv[14] + pv[15]);
        float rs = (t0 + t1) + (t2 + t3);
        rs += __shfl_xor(rs, 16);
        rs += __shfl_xor(rs, 32);
        l_r += rs;

        // P -> per-wave swizzled LDS (cvt_pk pack, 2 insts per 4 vals)
#pragma unroll
        for (int c = 0; c < 4; c++) {
            uint2 pr;
            pr.x = cvtpk(pv[c * 4 + 0], pv[c * 4 + 1]);
            pr.y = cvtpk(pv[c * 4 + 2], pv[c * 4 + 3]);
            int g = (c << 1) + (l4 >> 1);
            int gp = g ^ (l15 & 7);
            *(uint2*)&Pl[w * 1024 + l15 * 64 + gp * 8 + ((l4 & 1) << 2)] = pr;
        }

        __builtin_amdgcn_s_setprio(1);
#pragma unroll
        for (int kk = 0; kk < 2; kk++) {
            int grp = ((kk << 2) + l4) ^ (l15 & 7);
            bf16x8 pf = *(const bf16x8*)&Pl[w * 1024 + l15 * 64 + grp * 8];
#pragma unroll
            for (int dg = 0; dg < 4; dg++) {
                int drow = (dg << 4) + l15;
                bf16x8 vf = *(const bf16x8*)(&Vl[p][drow * 64 + grp * 8]);
                oacc[dg] = MFMA16(pf, vf, oacc[dg]);
            }
        }
        __builtin_amdgcn_s_setprio(0);
    };

    STAGE(0, 0);

    for (int kt = 0; kt < NT; kt++) {
        const int p = kt & 1;
        __syncthreads();  // all waves done with buf p^1 (prev step)
        if (kt + 1 < NT) {
            STAGE(kt + 1, p ^ 1);
            asm volatile("s_waitcnt vmcnt(4)" ::: "memory");
        } else {
            asm volatile("s_waitcnt vmcnt(0)" ::: "memory");
        }
        __syncthreads();  // this step's K/V landed for all waves

        const bool act0 = (kt <= qt0);

        // S-MFMAs: shared K fragments feed both halves
        f32x4 s1[4], s0[4];
        __builtin_amdgcn_s_setprio(1);
#pragma unroll
        for (int c = 0; c < 4; c++) {
            int trow = c * 16 + l15;
            int sw = l15 & 7;
            bf16x8 kf0 = *(const bf16x8*)(&Kl[p][trow * 64 + (l4 ^ sw) * 8]);
            bf16x8 kf1 = *(const bf16x8*)(&Kl[p][trow * 64 + ((4 + l4) ^ sw) * 8]);
            f32x4 a = zero;
            a = MFMA16(kf0, q1a, a);
            a = MFMA16(kf1, q1b, a);
            s1[c] = a;
            if (act0) {
                f32x4 b = zero;
                b = MFMA16(kf0, q0a, b);
                b = MFMA16(kf1, q0b, b);
                s0[c] = b;
            }
        }
        __builtin_amdgcn_s_setprio(0);

        SMPV(s1, m1, l1, o1, qrow1, kt == qt1, kt, p);
        if (act0) {
            // P region reused: ensure PV1's P reads retired before overwrite
            asm volatile("s_waitcnt lgkmcnt(0)" ::: "memory");
            SMPV(s0, m0, l0, o0, qrow0, kt == qt0, kt, p);
        }
    }

    // epilogue: normalize + write concat (B,T,C) bf16
    const int b = bh >> 4, hh = bh & 15;
    {
        float inv[4];
#pragma unroll
        for (int r = 0; r < 4; r++) inv[r] = 1.0f / __shfl(l0, l4 * 4 + r);
        int tb = qt0 * 64 + w * 16 + l4 * 4;
#pragma unroll
        for (int r = 0; r < 4; r++)
#pragma unroll
            for (int dg = 0; dg < 4; dg++)
                Oc[(b * TSEQ + tb + r) * CDIM + hh * DH + (dg << 4) + l15] =
                    f2bf(o0[dg][r] * inv[r]);
    }
    {
        float inv[4];
#pragma unroll
        for (int r = 0; r < 4; r++) inv[r] = 1.0f / __shfl(l1, l4 * 4 + r);
        int tb = qt1 * 64 + w * 16 + l4 * 4;
#pragma unroll
        for (int r = 0; r < 4; r++)
#pragma unroll
            for (int dg = 0; dg < 4; dg++)
                Oc[(b * TSEQ + tb + r) * CDIM + hh * DH + (dg << 4) + l15] =
                    f2bf(o1[dg][r] * inv[r]);
    }
}

extern "C" void kernel_launch(void* const* d_in, const int* in_sizes, int n_in,
                              void* d_out, int out_size, void* d_ws, size_t ws_size,
                              hipStream_t stream) {
    const float* x     = (const float*)d_in[0];
    const float* W_qkv = (const float*)d_in[1];
    const float* b_qkv = (const float*)d_in[2];
    const float* W_out = (const float*)d_in[3];
    const float* b_out = (const float*)d_in[4];
    float* out = (float*)d_out;

    u16* xb  = (u16*)d_ws;            // 8192*1024
    u16* Wqt = xb  + 8388608;         // 3072*1024
    u16* Wot = Wqt + 3145728;         // 1024*1024
    u16* Qw  = Wot + 1048576;         // 64*2048*64 (pre-scaled by SCLQ)
    u16* Kw  = Qw  + 8388608;
    u16* Vtw = Kw  + 8388608;         // V transposed [bh][d][t], written by qkv_gemm
    u16* Ocw = Vtw + 8388608;

    cvt_bf16<<<4096, 256, 0, stream>>>(x, xb, 8388608);
    tr_w_bf16<<<dim3(96, 32), dim3(32, 8), 0, stream>>>(W_qkv, Wqt, 1024, 3072);
    tr_w_bf16<<<dim3(32, 32), dim3(32, 8), 0, stream>>>(W_out, Wot, 1024, 1024);
    qkv_gemm_bf<<<dim3(24, 64), 256, 0, stream>>>(xb, Wqt, b_qkv, Qw, Kw, Vtw);
    attn_mfma<<<1024, 256, 0, stream>>>(Qw, Kw, Vtw, Ocw);
    out_gemm_bf<<<dim3(8, 64), 256, 0, stream>>>(Ocw, Wot, b_out, out);
}

// Round 5
// 266.255 us; speedup vs baseline: 7.2375x; 1.0213x over previous
//
#include <hip/hip_runtime.h>
#include <math.h>

typedef __attribute__((ext_vector_type(8))) short bf16x8;
typedef __attribute__((ext_vector_type(4))) float f32x4;
typedef unsigned short u16;
typedef unsigned int u32;

#define TSEQ 2048
#define NH   16
#define DH   64
#define CDIM 1024
#define SCLQ 0.18033688011112042f  // 0.125 * log2(e): folded into Q

__device__ __forceinline__ u16 f2bf(float f) {
    union { float f; u32 u; } v; v.f = f;
    u32 r = v.u + 0x7fffu + ((v.u >> 16) & 1u);
    return (u16)(r >> 16);
}

__device__ __forceinline__ u32 cvtpk(float lo, float hi) {
    u32 r;
    asm("v_cvt_pk_bf16_f32 %0, %1, %2" : "=v"(r) : "v"(lo), "v"(hi));
    return r;
}

__device__ __forceinline__ float max3f(float a, float b, float c) {
    return fmaxf(fmaxf(a, b), c);
}

__device__ __forceinline__ void gl_lds16(const void* g, void* l) {
    __builtin_amdgcn_global_load_lds(
        (const __attribute__((address_space(1))) u32*)g,
        (__attribute__((address_space(3))) u32*)l, 16, 0, 0);
}

#define MFMA16(a, b, c) __builtin_amdgcn_mfma_f32_16x16x32_bf16(a, b, c, 0, 0, 0)

#define BAR()   do { __builtin_amdgcn_s_barrier(); __builtin_amdgcn_sched_barrier(0); } while (0)
#define WAITV(n) do { asm volatile("s_waitcnt vmcnt(" #n ")" ::: "memory"); \
                      __builtin_amdgcn_sched_barrier(0); } while (0)
#define WAITL() do { asm volatile("s_waitcnt lgkmcnt(0)" ::: "memory"); \
                     __builtin_amdgcn_sched_barrier(0); } while (0)

// ---------------------------------------------------------------------------
// fp32 -> bf16 elementwise (x)
// ---------------------------------------------------------------------------
__global__ __launch_bounds__(256) void cvt_bf16(const float* __restrict__ in,
                                                u16* __restrict__ out, int n) {
    int i = (blockIdx.x * 256 + threadIdx.x) * 8;
    if (i >= n) return;
    float4 a = *(const float4*)(in + i);
    float4 b = *(const float4*)(in + i + 4);
    u16 o[8] = {f2bf(a.x), f2bf(a.y), f2bf(a.z), f2bf(a.w),
                f2bf(b.x), f2bf(b.y), f2bf(b.z), f2bf(b.w)};
    *(uint4*)(out + i) = *(const uint4*)o;
}

// ---------------------------------------------------------------------------
// fp32 W[K][N] -> bf16 Wt[N][K]  (32x32 tiles, block (32,8))
// ---------------------------------------------------------------------------
__global__ __launch_bounds__(256) void tr_w_bf16(const float* __restrict__ Wf,
                                                 u16* __restrict__ Wt, int K, int N) {
    __shared__ float tile[32][33];
    int n0 = blockIdx.x * 32, k0 = blockIdx.y * 32;
    int tx = threadIdx.x, ty = threadIdx.y;
#pragma unroll
    for (int r = 0; r < 4; r++)
        tile[ty + r * 8][tx] = Wf[(k0 + ty + r * 8) * N + n0 + tx];
    __syncthreads();
#pragma unroll
    for (int r = 0; r < 4; r++)
        Wt[(n0 + ty + r * 8) * K + k0 + tx] = f2bf(tile[tx][ty + r * 8]);
}

// ---------------------------------------------------------------------------
// 8-phase-style GEMM: C[M][N] = A[M][1024] @ Bt[N][1024]^T + bias
// BM=128, BN=256, BK=64, 512 threads (8 waves, 2Mx4N), per-wave 64x64.
// Double-buffered LDS, granule-XOR swizzle (conflict-free ds_read_b128),
// counted vmcnt(4) (never 0 in loop), setprio around MFMA clusters.
// Per K-tile: 2 phases x 16 MFMA. Stage units: A (16KB), B rgn0, B rgn1.
// Stage slots/iter (2 K-tiles): P0: B1(t1)->buf1 | P1: A,B0(t+2)->buf0 +
// WAITV(4) | P2: B1(t+2)->buf0 | P3: A,B0(t+3)->buf1 + WAITV(4).
// Tail: stage tile index wraps (t&15) to keep vmcnt counts uniform (safe:
// targets are dead regions).
// EPI: 0 = fp32 out + bias; 1 = qkv scatter (Q pre-scaled, K, V transposed).
// ---------------------------------------------------------------------------
template <int EPI>
__global__ __launch_bounds__(512, 2) void gemm_8p(
    const u16* __restrict__ A, const u16* __restrict__ Bt,
    const float* __restrict__ bias,
    u16* __restrict__ O0, u16* __restrict__ O1, u16* __restrict__ O2,
    float* __restrict__ Of) {
    __shared__ u16 lA[2][128 * 64];      // 32 KB
    __shared__ u16 lB[2][2][128 * 64];   // 64 KB  (region = n-frag pair)

    const int tid = threadIdx.x;
    const int lane = tid & 63, w = tid >> 6;
    const int l15 = lane & 15, l4 = lane >> 4;
    const int wm = w >> 2, wn = w & 3;

    // XCD-aware bijective swizzle (gridDim.x % 8 == 0 for both uses)
    const int nwg = gridDim.x, cpx = nwg >> 3;
    const int wg = (blockIdx.x & 7) * cpx + (blockIdx.x >> 3);
    const int mi = wg & 63, ni = wg >> 6;
    const int mb = mi * 128, nb = ni * 256;
    const int KD = 1024;

    auto stA = [&](int t, int p) {
        int kb = (t & 15) * 64;
#pragma unroll
        for (int s = 0; s < 2; s++) {
            int idx = s * 512 + tid;
            int row = idx >> 3, g = idx & 7;
            int gsw = g ^ (row & 7);
            gl_lds16(A + (size_t)(mb + row) * KD + kb + gsw * 8, &lA[p][idx * 8]);
        }
    };
    auto stB = [&](int t, int rb, int p) {
        int kb = (t & 15) * 64;
#pragma unroll
        for (int s = 0; s < 2; s++) {
            int idx = s * 512 + tid;
            int row = idx >> 3, g = idx & 7;
            int nrow = (row & 31) + ((row >> 5) << 6) + rb * 32;
            int gsw = g ^ (row & 7);
            gl_lds16(Bt + (size_t)(nb + nrow) * KD + kb + gsw * 8,
                     &lB[p][rb][idx * 8]);
        }
    };

    f32x4 zero = {0.f, 0.f, 0.f, 0.f};
    f32x4 acc[4][4];
#pragma unroll
    for (int i = 0; i < 4; i++)
#pragma unroll
        for (int j = 0; j < 4; j++) acc[i][j] = zero;

    const int sw = l15 & 7;
    const int aRow = wm * 64 + l15;          // + fm*16
    const int bRow = wn * 32 + l15;          // + (fn&1)*16
    const int g0 = (l4 ^ sw) * 8, g1 = ((4 + l4) ^ sw) * 8;

    // prologue: t0 {A,B0,B1}, t1 {A,B0}; vmcnt(4) leaves t1 units in flight
    stA(0, 0); stB(0, 0, 0); stB(0, 1, 0);
    stA(1, 1); stB(1, 0, 1);
    WAITV(4);
    BAR();

    bf16x8 af[4][2], b0[2][2], b1[2][2];

    for (int j = 0; j < 8; j++) {
        // ================= P0: tile 2j, buf0 — A + B rgn0; stage B1(2j+1)
#pragma unroll
        for (int fm = 0; fm < 4; fm++) {
            const u16* base = &lA[0][(aRow + fm * 16) * 64];
            af[fm][0] = *(const bf16x8*)(base + g0);
            af[fm][1] = *(const bf16x8*)(base + g1);
        }
#pragma unroll
        for (int fn = 0; fn < 2; fn++) {
            const u16* base = &lB[0][0][(bRow + fn * 16) * 64];
            b0[fn][0] = *(const bf16x8*)(base + g0);
            b0[fn][1] = *(const bf16x8*)(base + g1);
        }
        stB(2 * j + 1, 1, 1);
        BAR(); WAITL();
        __builtin_amdgcn_s_setprio(1);
#pragma unroll
        for (int fm = 0; fm < 4; fm++)
#pragma unroll
            for (int fn = 0; fn < 2; fn++) {
                acc[fm][fn] = MFMA16(af[fm][0], b0[fn][0], acc[fm][fn]);
                acc[fm][fn] = MFMA16(af[fm][1], b0[fn][1], acc[fm][fn]);
            }
        __builtin_amdgcn_s_setprio(0);
        BAR();
        // ================= P1: B rgn1 (buf0); stage A,B0(2j+2)->buf0; WAITV(4)
#pragma unroll
        for (int fn = 0; fn < 2; fn++) {
            const u16* base = &lB[0][1][(bRow + fn * 16) * 64];
            b1[fn][0] = *(const bf16x8*)(base + g0);
            b1[fn][1] = *(const bf16x8*)(base + g1);
        }
        stA(2 * j + 2, 0); stB(2 * j + 2, 0, 0);
        WAITV(4);
        BAR(); WAITL();
        __builtin_amdgcn_s_setprio(1);
#pragma unroll
        for (int fm = 0; fm < 4; fm++)
#pragma unroll
            for (int fn = 0; fn < 2; fn++) {
                acc[fm][fn + 2] = MFMA16(af[fm][0], b1[fn][0], acc[fm][fn + 2]);
                acc[fm][fn + 2] = MFMA16(af[fm][1], b1[fn][1], acc[fm][fn + 2]);
            }
        __builtin_amdgcn_s_setprio(0);
        BAR();
        // ================= P2: tile 2j+1, buf1 — A + B rgn0; stage B1(2j+2)
#pragma unroll
        for (int fm = 0; fm < 4; fm++) {
            const u16* base = &lA[1][(aRow + fm * 16) * 64];
            af[fm][0] = *(const bf16x8*)(base + g0);
            af[fm][1] = *(const bf16x8*)(base + g1);
        }
#pragma unroll
        for (int fn = 0; fn < 2; fn++) {
            const u16* base = &lB[1][0][(bRow + fn * 16) * 64];
            b0[fn][0] = *(const bf16x8*)(base + g0);
            b0[fn][1] = *(const bf16x8*)(base + g1);
        }
        stB(2 * j + 2, 1, 0);
        BAR(); WAITL();
        __builtin_amdgcn_s_setprio(1);
#pragma unroll
        for (int fm = 0; fm < 4; fm++)
#pragma unroll
            for (int fn = 0; fn < 2; fn++) {
                acc[fm][fn] = MFMA16(af[fm][0], b0[fn][0], acc[fm][fn]);
                acc[fm][fn] = MFMA16(af[fm][1], b0[fn][1], acc[fm][fn]);
            }
        __builtin_amdgcn_s_setprio(0);
        BAR();
        // ================= P3: B rgn1 (buf1); stage A,B0(2j+3)->buf1; WAITV(4)
#pragma unroll
        for (int fn = 0; fn < 2; fn++) {
            const u16* base = &lB[1][1][(bRow + fn * 16) * 64];
            b1[fn][0] = *(const bf16x8*)(base + g0);
            b1[fn][1] = *(const bf16x8*)(base + g1);
        }
        stA(2 * j + 3, 1); stB(2 * j + 3, 0, 1);
        WAITV(4);
        BAR(); WAITL();
        __builtin_amdgcn_s_setprio(1);
#pragma unroll
        for (int fm = 0; fm < 4; fm++)
#pragma unroll
            for (int fn = 0; fn < 2; fn++) {
                acc[fm][fn + 2] = MFMA16(af[fm][0], b1[fn][0], acc[fm][fn + 2]);
                acc[fm][fn + 2] = MFMA16(af[fm][1], b1[fn][1], acc[fm][fn + 2]);
            }
        __builtin_amdgcn_s_setprio(0);
        BAR();
    }
    asm volatile("s_waitcnt vmcnt(0)" ::: "memory");
    __builtin_amdgcn_sched_barrier(0);

    // epilogue
#pragma unroll
    for (int fm = 0; fm < 4; fm++)
#pragma unroll
        for (int fn = 0; fn < 4; fn++) {
            int n = nb + wn * 64 + fn * 16 + l15;
            int m0 = mb + wm * 64 + fm * 16 + l4 * 4;
            float bz = bias[n];
            if (EPI == 0) {
#pragma unroll
                for (int i = 0; i < 4; i++)
                    Of[(size_t)(m0 + i) * CDIM + n] = acc[fm][fn][i] + bz;
            } else {
                int which = n >> 10, hh = (n >> 6) & 15, d = n & 63;
                int b = m0 >> 11, t0 = m0 & 2047;
                if (which == 0) {
#pragma unroll
                    for (int i = 0; i < 4; i++)
                        O0[((b * NH + hh) * TSEQ + t0 + i) * DH + d] =
                            f2bf((acc[fm][fn][i] + bz) * SCLQ);
                } else if (which == 1) {
#pragma unroll
                    for (int i = 0; i < 4; i++)
                        O1[((b * NH + hh) * TSEQ + t0 + i) * DH + d] =
                            f2bf(acc[fm][fn][i] + bz);
                } else {
                    u16 ov[4];
#pragma unroll
                    for (int i = 0; i < 4; i++) ov[i] = f2bf(acc[fm][fn][i] + bz);
                    *(uint2*)&O2[((b * NH + hh) * DH + d) * TSEQ + t0] =
                        *(const uint2*)ov;
                }
            }
        }
}

// ---------------------------------------------------------------------------
// Flash attention v4 (unchanged from round 4)
// ---------------------------------------------------------------------------
__global__ __launch_bounds__(256, 4) void attn_mfma(
    const u16* __restrict__ Q, const u16* __restrict__ K,
    const u16* __restrict__ Vt, u16* __restrict__ Oc) {
    __shared__ u16 Kl[2][4096];
    __shared__ u16 Vl[2][4096];
    __shared__ u16 Pl[4096];

    const int tid = threadIdx.x;
    const int lane = tid & 63, w = tid >> 6;
    const int l15 = lane & 15, l4 = lane >> 4;
    const int bh = blockIdx.x & 63;
    const int pair = blockIdx.x >> 6;
    const int qt0 = pair, qt1 = 31 - pair;
    const int NT = qt1 + 1;

    const u16* Qb = Q + bh * TSEQ * DH;
    const u16* Kb = K + bh * TSEQ * DH;
    const u16* Vb = Vt + bh * DH * TSEQ;

    auto STAGE = [&](int kt, int p) {
#pragma unroll
        for (int r = 0; r < 2; r++) {
            int idx = r * 256 + tid;
            int row = idx >> 3, h = idx & 7;
            int hs = h ^ (row & 7);
            gl_lds16(Kb + (kt * 64 + row) * DH + hs * 8, &Kl[p][idx * 8]);
            gl_lds16(Vb + row * TSEQ + kt * 64 + hs * 8, &Vl[p][idx * 8]);
        }
    };

    const int qrow0 = qt0 * 64 + w * 16 + l15;
    const int qrow1 = qt1 * 64 + w * 16 + l15;
    bf16x8 q0a, q0b, q1a, q1b;
    {
        const u16* qp = Qb + qrow0 * DH + l4 * 8;
        q0a = *(const bf16x8*)(qp);
        q0b = *(const bf16x8*)(qp + 32);
    }
    {
        const u16* qp = Qb + qrow1 * DH + l4 * 8;
        q1a = *(const bf16x8*)(qp);
        q1b = *(const bf16x8*)(qp + 32);
    }

    f32x4 zero = {0.f, 0.f, 0.f, 0.f};
    f32x4 o0[4], o1[4];
    float m0 = -INFINITY, l0 = 0.f, m1 = -INFINITY, l1 = 0.f;
#pragma unroll
    for (int i = 0; i < 4; i++) { o0[i] = zero; o1[i] = zero; }

    auto SMPV = [&](f32x4* s, float& m_r, float& l_r, f32x4* oacc,
                    int q_row, bool domask, int kt, int p) {
        if (domask) {
#pragma unroll
            for (int c = 0; c < 4; c++)
#pragma unroll
                for (int i = 0; i < 4; i++) {
                    int kg = kt * 64 + c * 16 + l4 * 4 + i;
                    if (kg > q_row) s[c][i] = -INFINITY;
                }
        }
        float a0 = max3f(s[0][0], s[0][1], s[0][2]);
        float a1 = max3f(s[0][3], s[1][0], s[1][1]);
        float a2 = max3f(s[1][2], s[1][3], s[2][0]);
        float a3 = max3f(s[2][1], s[2][2], s[2][3]);
        float a4 = max3f(s[3][0], s[3][1], s[3][2]);
        float mx = max3f(max3f(a0, a1, a2), fmaxf(a3, a4), s[3][3]);
        mx = fmaxf(mx, __shfl_xor(mx, 16));
        mx = fmaxf(mx, __shfl_xor(mx, 32));
        if (!__all(mx <= m_r)) {
            float mnew = fmaxf(m_r, mx);
            float corr = __builtin_amdgcn_exp2f(m_r - mnew);
            l_r *= corr;
            float cr[4];
#pragma unroll
            for (int r = 0; r < 4; r++) cr[r] = __shfl(corr, l4 * 4 + r);
#pragma unroll
            for (int dg = 0; dg < 4; dg++)
#pragma unroll
                for (int r = 0; r < 4; r++) oacc[dg][r] *= cr[r];
            m_r = mnew;
        }
        float pv[16];
#pragma unroll
        for (int c = 0; c < 4; c++)
#pragma unroll
            for (int i = 0; i < 4; i++)
                pv[c * 4 + i] = __builtin_amdgcn_exp2f(s[c][i] - m_r);
        float t0 = (pv[0] + pv[1]) + (pv[2] + pv[3]);
        float t1 = (pv[4] + pv[5]) + (pv[6] + pv[7]);
        float t2 = (pv[8] + pv[9]) + (pv[10] + pv[11]);
        float t3 = (pv[12] + pv[13]) + (pv[14] + pv[15]);
        float rs = (t0 + t1) + (t2 + t3);
        rs += __shfl_xor(rs, 16);
        rs += __shfl_xor(rs, 32);
        l_r += rs;

#pragma unroll
        for (int c = 0; c < 4; c++) {
            uint2 pr;
            pr.x = cvtpk(pv[c * 4 + 0], pv[c * 4 + 1]);
            pr.y = cvtpk(pv[c * 4 + 2], pv[c * 4 + 3]);
            int g = (c << 1) + (l4 >> 1);
            int gp = g ^ (l15 & 7);
            *(uint2*)&Pl[w * 1024 + l15 * 64 + gp * 8 + ((l4 & 1) << 2)] = pr;
        }

        __builtin_amdgcn_s_setprio(1);
#pragma unroll
        for (int kk = 0; kk < 2; kk++) {
            int grp = ((kk << 2) + l4) ^ (l15 & 7);
            bf16x8 pf = *(const bf16x8*)&Pl[w * 1024 + l15 * 64 + grp * 8];
#pragma unroll
            for (int dg = 0; dg < 4; dg++) {
                int drow = (dg << 4) + l15;
                bf16x8 vf = *(const bf16x8*)(&Vl[p][drow * 64 + grp * 8]);
                oacc[dg] = MFMA16(pf, vf, oacc[dg]);
            }
        }
        __builtin_amdgcn_s_setprio(0);
    };

    STAGE(0, 0);

    for (int kt = 0; kt < NT; kt++) {
        const int p = kt & 1;
        __syncthreads();
        if (kt + 1 < NT) {
            STAGE(kt + 1, p ^ 1);
            asm volatile("s_waitcnt vmcnt(4)" ::: "memory");
        } else {
            asm volatile("s_waitcnt vmcnt(0)" ::: "memory");
        }
        __syncthreads();

        const bool act0 = (kt <= qt0);

        f32x4 s1[4], s0[4];
        __builtin_amdgcn_s_setprio(1);
#pragma unroll
        for (int c = 0; c < 4; c++) {
            int trow = c * 16 + l15;
            int swz = l15 & 7;
            bf16x8 kf0 = *(const bf16x8*)(&Kl[p][trow * 64 + (l4 ^ swz) * 8]);
            bf16x8 kf1 = *(const bf16x8*)(&Kl[p][trow * 64 + ((4 + l4) ^ swz) * 8]);
            f32x4 a = zero;
            a = MFMA16(kf0, q1a, a);
            a = MFMA16(kf1, q1b, a);
            s1[c] = a;
            if (act0) {
                f32x4 b = zero;
                b = MFMA16(kf0, q0a, b);
                b = MFMA16(kf1, q0b, b);
                s0[c] = b;
            }
        }
        __builtin_amdgcn_s_setprio(0);

        SMPV(s1, m1, l1, o1, qrow1, kt == qt1, kt, p);
        if (act0) {
            asm volatile("s_waitcnt lgkmcnt(0)" ::: "memory");
            SMPV(s0, m0, l0, o0, qrow0, kt == qt0, kt, p);
        }
    }

    const int b = bh >> 4, hh = bh & 15;
    {
        float inv[4];
#pragma unroll
        for (int r = 0; r < 4; r++) inv[r] = 1.0f / __shfl(l0, l4 * 4 + r);
        int tb = qt0 * 64 + w * 16 + l4 * 4;
#pragma unroll
        for (int r = 0; r < 4; r++)
#pragma unroll
            for (int dg = 0; dg < 4; dg++)
                Oc[(b * TSEQ + tb + r) * CDIM + hh * DH + (dg << 4) + l15] =
                    f2bf(o0[dg][r] * inv[r]);
    }
    {
        float inv[4];
#pragma unroll
        for (int r = 0; r < 4; r++) inv[r] = 1.0f / __shfl(l1, l4 * 4 + r);
        int tb = qt1 * 64 + w * 16 + l4 * 4;
#pragma unroll
        for (int r = 0; r < 4; r++)
#pragma unroll
            for (int dg = 0; dg < 4; dg++)
                Oc[(b * TSEQ + tb + r) * CDIM + hh * DH + (dg << 4) + l15] =
                    f2bf(o1[dg][r] * inv[r]);
    }
}

extern "C" void kernel_launch(void* const* d_in, const int* in_sizes, int n_in,
                              void* d_out, int out_size, void* d_ws, size_t ws_size,
                              hipStream_t stream) {
    const float* x     = (const float*)d_in[0];
    const float* W_qkv = (const float*)d_in[1];
    const float* b_qkv = (const float*)d_in[2];
    const float* W_out = (const float*)d_in[3];
    const float* b_out = (const float*)d_in[4];
    float* out = (float*)d_out;

    u16* xb  = (u16*)d_ws;            // 8192*1024
    u16* Wqt = xb  + 8388608;         // 3072*1024
    u16* Wot = Wqt + 3145728;         // 1024*1024
    u16* Qw  = Wot + 1048576;         // 64*2048*64 (pre-scaled by SCLQ)
    u16* Kw  = Qw  + 8388608;
    u16* Vtw = Kw  + 8388608;         // V transposed [bh][d][t]
    u16* Ocw = Vtw + 8388608;

    cvt_bf16<<<4096, 256, 0, stream>>>(x, xb, 8388608);
    tr_w_bf16<<<dim3(96, 32), dim3(32, 8), 0, stream>>>(W_qkv, Wqt, 1024, 3072);
    tr_w_bf16<<<dim3(32, 32), dim3(32, 8), 0, stream>>>(W_out, Wot, 1024, 1024);
    gemm_8p<1><<<768, 512, 0, stream>>>(xb, Wqt, b_qkv, Qw, Kw, Vtw, nullptr);
    attn_mfma<<<1024, 256, 0, stream>>>(Qw, Kw, Vtw, Ocw);
    gemm_8p<0><<<256, 512, 0, stream>>>(Ocw, Wot, b_out, nullptr, nullptr, nullptr, out);
}